// Round 2
// baseline (123987.317 us; speedup 1.0000x reference)
//
#include <hip/hip_runtime.h>
#include <hip/hip_bf16.h>

// Problem constants
constexpr int kN = 8192;
constexpr int kF = 256;
constexpr int kH = 512;
constexpr int kL = 512;
constexpr int kE = kN * 4;           // 32768 edges
constexpr int kG = 4 * kH;           // 2048 gate rows

__device__ __forceinline__ float sigm(float x) { return 1.f / (1.f + __expf(-x)); }

__device__ __forceinline__ float4 ld_bf4(const __hip_bfloat16* p) {
    uint2 u = *(const uint2*)p;
    float4 r;
    r.x = __uint_as_float(u.x << 16);
    r.y = __uint_as_float(u.x & 0xffff0000u);
    r.z = __uint_as_float(u.y << 16);
    r.w = __uint_as_float(u.y & 0xffff0000u);
    return r;
}

// ---------------------------------------------------------------------------
__global__ void k_init(float* __restrict__ out, const float* __restrict__ bdo,
                       int* __restrict__ flags) {
    int idx = blockIdx.x * 256 + threadIdx.x;
    if (idx < kE) out[idx] = bdo[0];
    if (idx < 64) flags[idx] = -1;
}

__global__ void k_zero(float* __restrict__ out) {
    int idx = blockIdx.x * 256 + threadIdx.x;
    if (idx < kE) out[idx] = 0.f;
}

// ---------------------------------------------------------------------------
// Recurrent kernel: 64 persistent blocks (32/dir), 256 threads each.
// Block b owns h-dims [b*16, b*16+16) -> 64 gate rows.
// Whh slice (64x512/4) and Wih slice (64x256/4) live in VGPRs.
// Input projection computed on the fly (phase C), overlapped with the poll.
// ---------------------------------------------------------------------------
__global__ __launch_bounds__(256, 1) void k_recur(
    const float* __restrict__ edges,
    const float* __restrict__ Wih_f, const float* __restrict__ Whh_f, const float* __restrict__ b_f,
    const float* __restrict__ Wih_b, const float* __restrict__ Whh_b, const float* __restrict__ b_b,
    const float* __restrict__ Wa, const float* __restrict__ ba,
    const float* __restrict__ Wao, const float* __restrict__ bao,
    __hip_bfloat16* __restrict__ arc_f, __hip_bfloat16* __restrict__ arc_b,
    float* __restrict__ xring, float* __restrict__ zpart, int* __restrict__ flags) {

    const int blk = blockIdx.x;
    const int dir = blk >> 5;
    const int b   = blk & 31;
    const float* __restrict__ Whh = dir ? Whh_b : Whh_f;
    const float* __restrict__ Wih = dir ? Wih_b : Wih_f;
    const float* __restrict__ bia = dir ? b_b  : b_f;
    __hip_bfloat16* __restrict__ arc = dir ? arc_b : arc_f;
    const int tid = threadIdx.x;

    // matvec roles: 64 gate rows x 4-way K split
    const int jl = tid >> 2, ks = tid & 3;
    const int Jg = (jl >> 4) * kH + b * 16 + (jl & 15);
    // gate / xproj / z roles: wave = arc, lane = gate row (or attention unit)
    const int d_g = tid >> 6, jl2 = tid & 63;
    const int Jg2 = (jl2 >> 4) * kH + b * 16 + (jl2 & 15);
    const int a_id = jl2;

    // Whh slice in VGPRs: row Jg, cols [ks*128, ks*128+128)
    float w[128];
    {
        const float* wr = Whh + (size_t)Jg * kH + ks * 128;
        #pragma unroll
        for (int kk = 0; kk < 128; kk++) w[kk] = wr[kk];
    }
    // Wih slice in VGPRs: row Jg2, cols [d_g*64, d_g*64+64)
    float wih[64];
    {
        const float* wr = Wih + (size_t)Jg2 * kF + d_g * 64;
        #pragma unroll
        for (int kk = 0; kk < 64; kk++) wih[kk] = wr[kk];
    }
    const float biasR = bia[Jg2];
    const float baR   = ba[a_id];
    const float WaoR  = Wao[a_id];
    const float baoR  = bao[0];
    const float wax0  = Wa[(size_t)a_id * 515 + 512];
    const float wax1  = Wa[(size_t)a_id * 515 + 513];
    const float wax2  = Wa[(size_t)a_id * 515 + 514];

    __shared__ __align__(16) float hprev[512];
    __shared__ float Mh[4][64];
    __shared__ float cring[4][16];
    __shared__ float gl[4][64];
    __shared__ float harcl[4][16];
    __shared__ float carcl[4][16];
    __shared__ float logit_l[4];
    __shared__ float WaS[64][17];
    __shared__ __align__(16) float x_s[4][256];
    __shared__ float xpart[4][4][64];

    for (int l2 = tid; l2 < 512; l2 += 256) hprev[l2] = 0.f;
    Mh[tid >> 6][tid & 63] = 0.f;
    if (tid < 64) cring[tid >> 4][tid & 15] = 0.f;
    for (int l2 = tid; l2 < 1024; l2 += 256)
        WaS[l2 >> 4][l2 & 15] = Wa[(size_t)(l2 >> 4) * 515 + b * 16 + (l2 & 15)];
    __syncthreads();

// phase C: gate-x part + zx for node nn (block-uniform), results per-thread
#define XPROJ(nn, XPOUT, ZXOUT) do {                                          \
        int row_;                                                             \
        if (dir == 0) row_ = (nn) * 4 + d_g;                                  \
        else { row_ = ((nn) + 1 + d_g) * 4 + d_g;                             \
               if (row_ > kE - 1) row_ = kE - 1; }                            \
        float4 xv_ = *(const float4*)(edges + (size_t)row_ * kF + 4 * jl2);   \
        *(float4*)(&x_s[d_g][4 * jl2]) = xv_;                                 \
        __syncthreads();                                                      \
        float p0_ = 0.f, p1_ = 0.f, p2_ = 0.f, p3_ = 0.f;                     \
        _Pragma("unroll")                                                     \
        for (int k4_ = 0; k4_ < 16; k4_++) {                                  \
            float4 a0_ = *(const float4*)&x_s[0][d_g * 64 + k4_ * 4];         \
            float4 a1_ = *(const float4*)&x_s[1][d_g * 64 + k4_ * 4];         \
            float4 a2_ = *(const float4*)&x_s[2][d_g * 64 + k4_ * 4];         \
            float4 a3_ = *(const float4*)&x_s[3][d_g * 64 + k4_ * 4];         \
            float w0_ = wih[k4_*4], w1_ = wih[k4_*4+1];                       \
            float w2_ = wih[k4_*4+2], w3_ = wih[k4_*4+3];                     \
            p0_ += w0_*a0_.x + w1_*a0_.y + w2_*a0_.z + w3_*a0_.w;             \
            p1_ += w0_*a1_.x + w1_*a1_.y + w2_*a1_.z + w3_*a1_.w;             \
            p2_ += w0_*a2_.x + w1_*a2_.y + w2_*a2_.z + w3_*a2_.w;             \
            p3_ += w0_*a3_.x + w1_*a3_.y + w2_*a3_.z + w3_*a3_.w;             \
        }                                                                     \
        xpart[d_g][0][jl2] = p0_; xpart[d_g][1][jl2] = p1_;                   \
        xpart[d_g][2][jl2] = p2_; xpart[d_g][3][jl2] = p3_;                   \
        __syncthreads();                                                      \
        XPOUT = biasR + xpart[0][d_g][jl2] + xpart[1][d_g][jl2]               \
                      + xpart[2][d_g][jl2] + xpart[3][d_g][jl2];              \
        ZXOUT = baR + wax0 * x_s[d_g][0] + wax1 * x_s[d_g][1]                 \
                    + wax2 * x_s[d_g][2];                                     \
    } while (0)

    const int i0 = dir ? kN - 1 : 0;
    float xp, zxv;
    XPROJ(i0, xp, zxv);

    int* const myflag = flags + dir * 32 + b;

    for (int t = 0; t < kN; t++) {
        const int i = dir ? kN - 1 - t : t;

        // ---- A: M[iprev] = hprev . Whh^T (own 64 rows) ----
        float acc = 0.f;
        {
            const float* hp = &hprev[ks * 128];
            #pragma unroll
            for (int kk = 0; kk < 128; kk += 4) {
                float4 hv = *(const float4*)(hp + kk);
                acc += w[kk] * hv.x + w[kk+1] * hv.y + w[kk+2] * hv.z + w[kk+3] * hv.w;
            }
        }
        acc += __shfl_xor(acc, 1);
        acc += __shfl_xor(acc, 2);
        const int iprev = dir ? i + 1 : i - 1;
        if (ks == 0) Mh[iprev & 3][jl] = acc;
        __syncthreads();

        // ---- B: gates, LSTM, publish h_arc slice + z partials ----
        {
            const int p = dir ? i + 1 + d_g : i - 1 - d_g;
            gl[d_g][jl2] = xp + Mh[p & 3][jl2];
        }
        __syncthreads();
        if (tid < 64) {
            const int d3 = tid >> 4, s3 = tid & 15;
            const int pp = dir ? i + 1 + d3 : i - 1 - d3;
            const bool v3 = dir ? (pp < kN) : (pp >= 0);
            float gi = gl[d3][s3],      gf = gl[d3][16 + s3];
            float gg = gl[d3][32 + s3], go = gl[d3][48 + s3];
            float cp = cring[pp & 3][s3];
            float c = sigm(gf) * cp + sigm(gi) * tanhf(gg);
            float h = sigm(go) * tanhf(c);
            float hm = v3 ? h : 0.f, cm = v3 ? c : 0.f;
            harcl[d3][s3] = hm; carcl[d3][s3] = cm;
            __hip_atomic_store(&xring[(((dir * 2 + (t & 1)) * 4 + d3) << 9) + b * 16 + s3],
                               hm, __ATOMIC_RELAXED, __HIP_MEMORY_SCOPE_AGENT);
            arc[((size_t)i * 4 + d3) * kH + b * 16 + s3] = __float2bfloat16(hm);
        }
        __syncthreads();
        {
            float zp = 0.f;
            #pragma unroll
            for (int ss = 0; ss < 16; ss++) zp += WaS[a_id][ss] * harcl[d_g][ss];
            __hip_atomic_store(&zpart[(((dir * 2 + (t & 1)) * 32 + b) << 8) + tid],
                               zp, __ATOMIC_RELAXED, __HIP_MEMORY_SCOPE_AGENT);
        }
        __syncthreads();   // vmcnt(0): all device-scope stores drained
        if (tid == 0)
            __hip_atomic_store(myflag, t, __ATOMIC_RELEASE, __HIP_MEMORY_SCOPE_AGENT);

        // ---- C: next step's input projection (overlaps the poll window) ----
        float xp_n = 0.f, zx_n = 0.f;
        if (t + 1 < kN) {
            const int inext = dir ? i - 1 : i + 1;
            XPROJ(inext, xp_n, zx_n);
        }

        // ---- D: poll all 32 flags of this direction, then barrier ----
        if (tid < 64) {
            const int* pf = flags + dir * 32 + (tid & 31);
            while (__hip_atomic_load(pf, __ATOMIC_RELAXED, __HIP_MEMORY_SCOPE_AGENT) < t) {}
        }
        __syncthreads();   // now ALL 32 flags >= t for every thread
        __threadfence();

        // ---- E: z totals -> logits -> softmax -> h_node / c_node ----
        float zsum = 0.f;
        {
            const size_t zb = ((size_t)(dir * 2 + (t & 1)) << 13) + tid;
            #pragma unroll
            for (int bb = 0; bb < 32; bb++)
                zsum += __hip_atomic_load(&zpart[zb + ((size_t)bb << 8)],
                                          __ATOMIC_RELAXED, __HIP_MEMORY_SCOPE_AGENT);
        }
        float zv = fmaxf(zsum + zxv, 0.f);
        float lv = WaoR * zv;
        #pragma unroll
        for (int o2 = 1; o2 < 64; o2 <<= 1) lv += __shfl_xor(lv, o2);
        if (a_id == 0) {
            const int pp = dir ? i + 1 + d_g : i - 1 - d_g;
            const bool v3 = dir ? (pp < kN) : (pp >= 0);
            logit_l[d_g] = v3 ? tanhf(lv + baoR) : -1e9f;
        }
        __syncthreads();

        float l0 = logit_l[0], l1 = logit_l[1], l2 = logit_l[2], l3 = logit_l[3];
        float mx = fmaxf(fmaxf(l0, l1), fmaxf(l2, l3));
        float e0 = __expf(l0 - mx), e1 = __expf(l1 - mx);
        float e2 = __expf(l2 - mx), e3 = __expf(l3 - mx);
        float inv = 1.f / (e0 + e1 + e2 + e3);
        float wg[4] = { e0 * inv, e1 * inv, e2 * inv, e3 * inv };

        {
            const int base = ((dir * 2 + (t & 1)) * 4) << 9;
            float hn0 = 0.f, hn1 = 0.f;
            #pragma unroll
            for (int dd = 0; dd < 4; dd++) {
                float a0 = __hip_atomic_load(&xring[base + (dd << 9) + 2 * tid],
                                             __ATOMIC_RELAXED, __HIP_MEMORY_SCOPE_AGENT);
                float a1 = __hip_atomic_load(&xring[base + (dd << 9) + 2 * tid + 1],
                                             __ATOMIC_RELAXED, __HIP_MEMORY_SCOPE_AGENT);
                hn0 += wg[dd] * a0; hn1 += wg[dd] * a1;
            }
            hprev[2 * tid]     = hn0;
            hprev[2 * tid + 1] = hn1;
        }
        if (tid < 16) {
            float cn = wg[0] * carcl[0][tid] + wg[1] * carcl[1][tid]
                     + wg[2] * carcl[2][tid] + wg[3] * carcl[3][tid];
            cring[i & 3][tid] = cn;
        }
        __syncthreads();

        xp = xp_n; zxv = zx_n;
    }
#undef XPROJ
}

// ---------------------------------------------------------------------------
// decoder: out[e] += sum_l Wdo[l] * relu(bd[l] + sum_k Wd[l,k] feat[e,k])
// feat[e,k<512] = arc_f[e][k] (bf16); feat[e,512+k] = arc_b[(j-1-d)*4+d][k]
// ---------------------------------------------------------------------------
__global__ __launch_bounds__(256) void k_dec(
    const __hip_bfloat16* __restrict__ arc_f, const __hip_bfloat16* __restrict__ arc_b,
    const float* __restrict__ Wd, const float* __restrict__ bd,
    const float* __restrict__ Wdo, float* __restrict__ out) {
    const int e0 = blockIdx.x * 128;
    const int l0 = blockIdx.y * 128;
    __shared__ __align__(16) float As[8][128];
    __shared__ __align__(16) float Bs[8][128];
    const int tid = threadIdx.x;
    const int tx = tid & 15, ty = tid >> 4;
    const int lr = tid & 127, kq = tid >> 7;

    const int e = e0 + lr;
    const int j = e >> 2, d = e & 3;
    const int jb = j - 1 - d;
    const __hip_bfloat16* frow  = arc_f + (size_t)e * kH;
    const __hip_bfloat16* brow2 = (jb >= 0) ? (arc_b + ((size_t)jb * 4 + d) * kH) : nullptr;
    const float* wrow = Wd + (size_t)(l0 + lr) * (2 * kH);

    float acc[8][8] = {};
    for (int k0 = 0; k0 < 2 * kH; k0 += 8) {
        const int kk = k0 + kq * 4;
        float4 av4;
        if (kk < kH) av4 = ld_bf4(frow + kk);
        else if (brow2) av4 = ld_bf4(brow2 + (kk - kH));
        else av4 = make_float4(0.f, 0.f, 0.f, 0.f);
        float4 bv4 = *(const float4*)(wrow + kk);
        __syncthreads();
        As[kq*4+0][lr] = av4.x; As[kq*4+1][lr] = av4.y;
        As[kq*4+2][lr] = av4.z; As[kq*4+3][lr] = av4.w;
        Bs[kq*4+0][lr] = bv4.x; Bs[kq*4+1][lr] = bv4.y;
        Bs[kq*4+2][lr] = bv4.z; Bs[kq*4+3][lr] = bv4.w;
        __syncthreads();
        #pragma unroll
        for (int kt = 0; kt < 8; kt++) {
            __align__(16) float a0[8], b0[8];
            *(float4*)&a0[0] = *(const float4*)&As[kt][ty*8];
            *(float4*)&a0[4] = *(const float4*)&As[kt][ty*8+4];
            *(float4*)&b0[0] = *(const float4*)&Bs[kt][tx*8];
            *(float4*)&b0[4] = *(const float4*)&Bs[kt][tx*8+4];
            #pragma unroll
            for (int mi = 0; mi < 8; mi++)
                #pragma unroll
                for (int ni = 0; ni < 8; ni++)
                    acc[mi][ni] += a0[mi] * b0[ni];
        }
    }
    #pragma unroll
    for (int mi = 0; mi < 8; mi++) {
        float sacc = 0.f;
        #pragma unroll
        for (int ni = 0; ni < 8; ni++) {
            int l = l0 + tx * 8 + ni;
            sacc += Wdo[l] * fmaxf(acc[mi][ni] + bd[l], 0.f);
        }
        sacc += __shfl_xor(sacc, 1);
        sacc += __shfl_xor(sacc, 2);
        sacc += __shfl_xor(sacc, 4);
        sacc += __shfl_xor(sacc, 8);
        if (tx == 0) atomicAdd(out + e0 + ty * 8 + mi, sacc);
    }
}

// ---------------------------------------------------------------------------
extern "C" void kernel_launch(void* const* d_in, const int* in_sizes, int n_in,
                              void* d_out, int out_size, void* d_ws, size_t ws_size,
                              hipStream_t stream) {
    const float* edges = (const float*)d_in[0];
    const float* Wih_f = (const float*)d_in[1];
    const float* Whh_f = (const float*)d_in[2];
    const float* b_f   = (const float*)d_in[3];
    const float* Wih_b = (const float*)d_in[4];
    const float* Whh_b = (const float*)d_in[5];
    const float* b_b   = (const float*)d_in[6];
    const float* Wa    = (const float*)d_in[7];
    const float* ba    = (const float*)d_in[8];
    const float* Wao   = (const float*)d_in[9];
    const float* bao   = (const float*)d_in[10];
    const float* Wd    = (const float*)d_in[11];
    const float* bd    = (const float*)d_in[12];
    const float* Wdo   = (const float*)d_in[13];
    const float* bdo   = (const float*)d_in[14];
    float* out = (float*)d_out;

    char* ws = (char*)d_ws;
    size_t off = 0;
    __hip_bfloat16* arc_f = (__hip_bfloat16*)(ws + off); off += (size_t)kE * kH * 2;  // 32 MB
    __hip_bfloat16* arc_b = (__hip_bfloat16*)(ws + off); off += (size_t)kE * kH * 2;  // 32 MB
    float* xring = (float*)(ws + off); off += (size_t)2 * 2 * 4 * kH * 4;             // 32 KB
    float* zpart = (float*)(ws + off); off += (size_t)2 * 2 * 32 * 256 * 4;           // 128 KB
    int*   flags = (int*)  (ws + off); off += 256;

    if (ws_size < off) {
        hipLaunchKernelGGL(k_zero, dim3((kE + 255) / 256), dim3(256), 0, stream, out);
        return;
    }

    hipLaunchKernelGGL(k_init, dim3((kE + 255) / 256), dim3(256), 0, stream,
                       out, bdo, flags);
    hipLaunchKernelGGL(k_recur, dim3(64), dim3(256), 0, stream,
                       edges, Wih_f, Whh_f, b_f, Wih_b, Whh_b, b_b,
                       Wa, ba, Wao, bao, arc_f, arc_b, xring, zpart, flags);
    hipLaunchKernelGGL(k_dec, dim3(kE / 128, kL / 128), dim3(256), 0, stream,
                       arc_f, arc_b, Wd, bd, Wdo, out);
}

// Round 3
// 49504.913 us; speedup vs baseline: 2.5045x; 2.5045x over previous
//
#include <hip/hip_runtime.h>
#include <hip/hip_bf16.h>

// Problem constants
constexpr int kN = 8192;
constexpr int kF = 256;
constexpr int kH = 512;
constexpr int kL = 512;
constexpr int kE = kN * 4;           // 32768 edges

using ull = unsigned long long;

__device__ __forceinline__ float sigm(float x) { return 1.f / (1.f + __expf(-x)); }

__device__ __forceinline__ float4 ld_bf4(const __hip_bfloat16* p) {
    uint2 u = *(const uint2*)p;
    float4 r;
    r.x = __uint_as_float(u.x << 16);
    r.y = __uint_as_float(u.x & 0xffff0000u);
    r.z = __uint_as_float(u.y << 16);
    r.w = __uint_as_float(u.y & 0xffff0000u);
    return r;
}

// stamped 8-byte pair: low = float bits, high = stamp (step+1)
__device__ __forceinline__ void st_pair(ull* p, float v, unsigned stamp) {
    ull u = ((ull)stamp << 32) | (ull)__float_as_uint(v);
    __hip_atomic_store(p, u, __ATOMIC_RELAXED, __HIP_MEMORY_SCOPE_AGENT);
}
__device__ __forceinline__ ull ld_raw(const ull* p) {
    return __hip_atomic_load(p, __ATOMIC_RELAXED, __HIP_MEMORY_SCOPE_AGENT);
}

// ---------------------------------------------------------------------------
__global__ void k_init(float* __restrict__ out, const float* __restrict__ bdo,
                       ull* __restrict__ hpay, ull* __restrict__ zpay) {
    int idx = blockIdx.x * 256 + threadIdx.x;
    if (idx < kE) out[idx] = bdo[0];
    if (idx < 2 * 2 * 4 * kH) hpay[idx] = 0ull;
    if (idx < 2 * 2 * 32 * 256) zpay[idx] = 0ull;
}

__global__ void k_zero(float* __restrict__ out) {
    int idx = blockIdx.x * 256 + threadIdx.x;
    if (idx < kE) out[idx] = 0.f;
}

// ---------------------------------------------------------------------------
// Recurrent kernel: 64 persistent blocks (32/dir), 256 threads each.
// Block b owns h-dims [b*16, b*16+16) -> 64 gate rows (Whh slice in VGPRs).
// Cross-block exchange: stamped 64-bit pairs, relaxed agent atomics only —
// NO fences, NO flags, NO L2 invalidation.
// ---------------------------------------------------------------------------
__global__ __launch_bounds__(256, 1) void k_recur(
    const float* __restrict__ edges,
    const float* __restrict__ Wih_f, const float* __restrict__ Whh_f, const float* __restrict__ b_f,
    const float* __restrict__ Wih_b, const float* __restrict__ Whh_b, const float* __restrict__ b_b,
    const float* __restrict__ Wa, const float* __restrict__ ba,
    const float* __restrict__ Wao, const float* __restrict__ bao,
    __hip_bfloat16* __restrict__ arc_f, __hip_bfloat16* __restrict__ arc_b,
    ull* __restrict__ hpay, ull* __restrict__ zpay) {

    const int blk = blockIdx.x;
    const int dir = blk >> 5;
    const int b   = blk & 31;
    const float* __restrict__ Whh = dir ? Whh_b : Whh_f;
    const float* __restrict__ Wih = dir ? Wih_b : Wih_f;
    const float* __restrict__ bia = dir ? b_b  : b_f;
    __hip_bfloat16* __restrict__ arc = dir ? arc_b : arc_f;
    const int tid = threadIdx.x;

    // matvec roles: 64 gate rows x 4-way K split
    const int jl = tid >> 2, ks = tid & 3;
    const int Jg = (jl >> 4) * kH + b * 16 + (jl & 15);
    // gate / xproj / z roles: wave = arc, lane = gate row (or attention unit)
    const int d_g = tid >> 6, jl2 = tid & 63;
    const int Jg2 = (jl2 >> 4) * kH + b * 16 + (jl2 & 15);
    const int a_id = jl2;

    float w[128];
    {
        const float* wr = Whh + (size_t)Jg * kH + ks * 128;
        #pragma unroll
        for (int kk = 0; kk < 128; kk++) w[kk] = wr[kk];
    }
    float wih[64];
    {
        const float* wr = Wih + (size_t)Jg2 * kF + d_g * 64;
        #pragma unroll
        for (int kk = 0; kk < 64; kk++) wih[kk] = wr[kk];
    }
    const float biasR = bia[Jg2];
    const float baR   = ba[a_id];
    const float WaoR  = Wao[a_id];
    const float baoR  = bao[0];
    const float wax0  = Wa[(size_t)a_id * 515 + 512];
    const float wax1  = Wa[(size_t)a_id * 515 + 513];
    const float wax2  = Wa[(size_t)a_id * 515 + 514];

    // hprev padded: 4 chunks of 132 floats (banks offset 4 per chunk -> no conflict)
    __shared__ __align__(16) float hprev_p[4 * 132];
    __shared__ float Mh[4][64];
    __shared__ float cring[4][16];
    __shared__ float gl[4][64];
    __shared__ float harcl[4][16];
    __shared__ float carcl[4][16];
    __shared__ float logit_l[4];
    __shared__ float WaS[64][17];
    __shared__ __align__(16) float x_s[4][256];
    __shared__ float xpart[4][4][64];

    for (int l2 = tid; l2 < 4 * 132; l2 += 256) hprev_p[l2] = 0.f;
    Mh[tid >> 6][tid & 63] = 0.f;
    if (tid < 64) cring[tid >> 4][tid & 15] = 0.f;
    for (int l2 = tid; l2 < 1024; l2 += 256)
        WaS[l2 >> 4][l2 & 15] = Wa[(size_t)(l2 >> 4) * 515 + b * 16 + (l2 & 15)];
    __syncthreads();

// phase C: gate-x part + zx for node nn (block-uniform), results per-thread
#define XPROJ(nn, XPOUT, ZXOUT) do {                                          \
        int row_;                                                             \
        if (dir == 0) row_ = (nn) * 4 + d_g;                                  \
        else { row_ = ((nn) + 1 + d_g) * 4 + d_g;                             \
               if (row_ > kE - 1) row_ = kE - 1; }                            \
        float4 xv_ = *(const float4*)(edges + (size_t)row_ * kF + 4 * jl2);   \
        *(float4*)(&x_s[d_g][4 * jl2]) = xv_;                                 \
        __syncthreads();                                                      \
        float p0_ = 0.f, p1_ = 0.f, p2_ = 0.f, p3_ = 0.f;                     \
        _Pragma("unroll")                                                     \
        for (int k4_ = 0; k4_ < 16; k4_++) {                                  \
            float4 a0_ = *(const float4*)&x_s[0][d_g * 64 + k4_ * 4];         \
            float4 a1_ = *(const float4*)&x_s[1][d_g * 64 + k4_ * 4];         \
            float4 a2_ = *(const float4*)&x_s[2][d_g * 64 + k4_ * 4];         \
            float4 a3_ = *(const float4*)&x_s[3][d_g * 64 + k4_ * 4];         \
            float w0_ = wih[k4_*4], w1_ = wih[k4_*4+1];                       \
            float w2_ = wih[k4_*4+2], w3_ = wih[k4_*4+3];                     \
            p0_ += w0_*a0_.x + w1_*a0_.y + w2_*a0_.z + w3_*a0_.w;             \
            p1_ += w0_*a1_.x + w1_*a1_.y + w2_*a1_.z + w3_*a1_.w;             \
            p2_ += w0_*a2_.x + w1_*a2_.y + w2_*a2_.z + w3_*a2_.w;             \
            p3_ += w0_*a3_.x + w1_*a3_.y + w2_*a3_.z + w3_*a3_.w;             \
        }                                                                     \
        xpart[d_g][0][jl2] = p0_; xpart[d_g][1][jl2] = p1_;                   \
        xpart[d_g][2][jl2] = p2_; xpart[d_g][3][jl2] = p3_;                   \
        __syncthreads();                                                      \
        XPOUT = biasR + xpart[0][d_g][jl2] + xpart[1][d_g][jl2]               \
                      + xpart[2][d_g][jl2] + xpart[3][d_g][jl2];              \
        ZXOUT = baR + wax0 * x_s[d_g][0] + wax1 * x_s[d_g][1]                 \
                    + wax2 * x_s[d_g][2];                                     \
    } while (0)

    const int i0 = dir ? kN - 1 : 0;
    float xp, zxv;
    XPROJ(i0, xp, zxv);

    for (int t = 0; t < kN; t++) {
        const int i = dir ? kN - 1 - t : t;
        const unsigned stamp = (unsigned)(t + 1);
        const int par = t & 1;

        // ---- A: M[iprev] = hprev . Whh^T (own 64 rows) ----
        float acc = 0.f;
        {
            const float* hp = &hprev_p[ks * 132];
            #pragma unroll
            for (int kk = 0; kk < 128; kk += 4) {
                float4 hv = *(const float4*)(hp + kk);
                acc += w[kk] * hv.x + w[kk+1] * hv.y + w[kk+2] * hv.z + w[kk+3] * hv.w;
            }
        }
        acc += __shfl_xor(acc, 1);
        acc += __shfl_xor(acc, 2);
        const int iprev = dir ? i + 1 : i - 1;
        if (ks == 0) Mh[iprev & 3][jl] = acc;
        __syncthreads();

        // ---- B: gates ----
        {
            const int p = dir ? i + 1 + d_g : i - 1 - d_g;
            gl[d_g][jl2] = xp + Mh[p & 3][jl2];
        }
        __syncthreads();
        if (tid < 64) {
            const int d3 = tid >> 4, s3 = tid & 15;
            const int pp = dir ? i + 1 + d3 : i - 1 - d3;
            const bool v3 = dir ? (pp < kN) : (pp >= 0);
            float gi = gl[d3][s3],      gf = gl[d3][16 + s3];
            float gg = gl[d3][32 + s3], go = gl[d3][48 + s3];
            float cp = cring[pp & 3][s3];
            float c = sigm(gf) * cp + sigm(gi) * tanhf(gg);
            float h = sigm(go) * tanhf(c);
            float hm = v3 ? h : 0.f, cm = v3 ? c : 0.f;
            harcl[d3][s3] = hm; carcl[d3][s3] = cm;
            arc[((size_t)i * 4 + d3) * kH + b * 16 + s3] = __float2bfloat16(hm);
            st_pair(hpay + (((dir * 2 + par) * 4 + d3) << 9) + b * 16 + s3, hm, stamp);
        }
        __syncthreads();
        // z partials over own 16 h-dims, publish
        {
            float zp = 0.f;
            #pragma unroll
            for (int ss = 0; ss < 16; ss++) zp += WaS[a_id][ss] * harcl[d_g][ss];
            st_pair(zpay + (((dir * 2 + par) * 32 + b) << 8) + tid, zp, stamp);
        }

        // ---- C: next step's input projection (overlaps publish latency) ----
        float xp_n = 0.f, zx_n = 0.f;
        if (t + 1 < kN) {
            const int inext = dir ? i - 1 : i + 1;
            XPROJ(inext, xp_n, zx_n);
        }

        // ---- E: batched stamped loads (z + h), then resolve ----
        const ull* zb = zpay + (((size_t)(dir * 2 + par) * 32) << 8) + tid;
        ull zv_[32];
        #pragma unroll
        for (int bb = 0; bb < 32; bb++) zv_[bb] = ld_raw(zb + ((size_t)bb << 8));
        const ull* hb = hpay + (((size_t)(dir * 2 + par) * 4) << 9);
        ull hv_[8];
        #pragma unroll
        for (int dd = 0; dd < 4; dd++) {
            hv_[2*dd]   = ld_raw(hb + (dd << 9) + 2 * tid);
            hv_[2*dd+1] = ld_raw(hb + (dd << 9) + 2 * tid + 1);
        }

        float zsum = 0.f;
        #pragma unroll
        for (int bb = 0; bb < 32; bb++) {
            ull u = zv_[bb];
            while ((unsigned)(u >> 32) != stamp) u = ld_raw(zb + ((size_t)bb << 8));
            zsum += __uint_as_float((unsigned)u);
        }
        float zv = fmaxf(zsum + zxv, 0.f);
        float lv = WaoR * zv;
        #pragma unroll
        for (int o2 = 1; o2 < 64; o2 <<= 1) lv += __shfl_xor(lv, o2);
        if (a_id == 0) {
            const int pp = dir ? i + 1 + d_g : i - 1 - d_g;
            const bool v3 = dir ? (pp < kN) : (pp >= 0);
            logit_l[d_g] = v3 ? tanhf(lv + baoR) : -1e9f;
        }
        __syncthreads();

        float l0 = logit_l[0], l1 = logit_l[1], l2 = logit_l[2], l3 = logit_l[3];
        float mx = fmaxf(fmaxf(l0, l1), fmaxf(l2, l3));
        float e0 = __expf(l0 - mx), e1 = __expf(l1 - mx);
        float e2 = __expf(l2 - mx), e3 = __expf(l3 - mx);
        float inv = 1.f / (e0 + e1 + e2 + e3);
        float wg[4] = { e0 * inv, e1 * inv, e2 * inv, e3 * inv };

        float hn0 = 0.f, hn1 = 0.f;
        #pragma unroll
        for (int dd = 0; dd < 4; dd++) {
            ull u0 = hv_[2*dd], u1 = hv_[2*dd+1];
            while ((unsigned)(u0 >> 32) != stamp) u0 = ld_raw(hb + (dd << 9) + 2 * tid);
            while ((unsigned)(u1 >> 32) != stamp) u1 = ld_raw(hb + (dd << 9) + 2 * tid + 1);
            hn0 += wg[dd] * __uint_as_float((unsigned)u0);
            hn1 += wg[dd] * __uint_as_float((unsigned)u1);
        }
        {
            const int g = 2 * tid;
            const int ch = g >> 7, wi = g & 127;
            hprev_p[ch * 132 + wi]     = hn0;
            hprev_p[ch * 132 + wi + 1] = hn1;
        }
        if (tid < 16) {
            float cn = wg[0] * carcl[0][tid] + wg[1] * carcl[1][tid]
                     + wg[2] * carcl[2][tid] + wg[3] * carcl[3][tid];
            cring[i & 3][tid] = cn;
        }
        __syncthreads();

        xp = xp_n; zxv = zx_n;
    }
#undef XPROJ
}

// ---------------------------------------------------------------------------
// decoder: out[e] += sum_l Wdo[l] * relu(bd[l] + sum_k Wd[l,k] feat[e,k])
// ---------------------------------------------------------------------------
__global__ __launch_bounds__(256) void k_dec(
    const __hip_bfloat16* __restrict__ arc_f, const __hip_bfloat16* __restrict__ arc_b,
    const float* __restrict__ Wd, const float* __restrict__ bd,
    const float* __restrict__ Wdo, float* __restrict__ out) {
    const int e0 = blockIdx.x * 128;
    const int l0 = blockIdx.y * 128;
    __shared__ __align__(16) float As[8][128];
    __shared__ __align__(16) float Bs[8][128];
    const int tid = threadIdx.x;
    const int tx = tid & 15, ty = tid >> 4;
    const int lr = tid & 127, kq = tid >> 7;

    const int e = e0 + lr;
    const int j = e >> 2, d = e & 3;
    const int jb = j - 1 - d;
    const __hip_bfloat16* frow  = arc_f + (size_t)e * kH;
    const __hip_bfloat16* brow2 = (jb >= 0) ? (arc_b + ((size_t)jb * 4 + d) * kH) : nullptr;
    const float* wrow = Wd + (size_t)(l0 + lr) * (2 * kH);

    float acc[8][8] = {};
    for (int k0 = 0; k0 < 2 * kH; k0 += 8) {
        const int kk = k0 + kq * 4;
        float4 av4;
        if (kk < kH) av4 = ld_bf4(frow + kk);
        else if (brow2) av4 = ld_bf4(brow2 + (kk - kH));
        else av4 = make_float4(0.f, 0.f, 0.f, 0.f);
        float4 bv4 = *(const float4*)(wrow + kk);
        __syncthreads();
        As[kq*4+0][lr] = av4.x; As[kq*4+1][lr] = av4.y;
        As[kq*4+2][lr] = av4.z; As[kq*4+3][lr] = av4.w;
        Bs[kq*4+0][lr] = bv4.x; Bs[kq*4+1][lr] = bv4.y;
        Bs[kq*4+2][lr] = bv4.z; Bs[kq*4+3][lr] = bv4.w;
        __syncthreads();
        #pragma unroll
        for (int kt = 0; kt < 8; kt++) {
            __align__(16) float a0[8], b0[8];
            *(float4*)&a0[0] = *(const float4*)&As[kt][ty*8];
            *(float4*)&a0[4] = *(const float4*)&As[kt][ty*8+4];
            *(float4*)&b0[0] = *(const float4*)&Bs[kt][tx*8];
            *(float4*)&b0[4] = *(const float4*)&Bs[kt][tx*8+4];
            #pragma unroll
            for (int mi = 0; mi < 8; mi++)
                #pragma unroll
                for (int ni = 0; ni < 8; ni++)
                    acc[mi][ni] += a0[mi] * b0[ni];
        }
    }
    #pragma unroll
    for (int mi = 0; mi < 8; mi++) {
        float sacc = 0.f;
        #pragma unroll
        for (int ni = 0; ni < 8; ni++) {
            int l = l0 + tx * 8 + ni;
            sacc += Wdo[l] * fmaxf(acc[mi][ni] + bd[l], 0.f);
        }
        sacc += __shfl_xor(sacc, 1);
        sacc += __shfl_xor(sacc, 2);
        sacc += __shfl_xor(sacc, 4);
        sacc += __shfl_xor(sacc, 8);
        if (tx == 0) atomicAdd(out + e0 + ty * 8 + mi, sacc);
    }
}

// ---------------------------------------------------------------------------
extern "C" void kernel_launch(void* const* d_in, const int* in_sizes, int n_in,
                              void* d_out, int out_size, void* d_ws, size_t ws_size,
                              hipStream_t stream) {
    const float* edges = (const float*)d_in[0];
    const float* Wih_f = (const float*)d_in[1];
    const float* Whh_f = (const float*)d_in[2];
    const float* b_f   = (const float*)d_in[3];
    const float* Wih_b = (const float*)d_in[4];
    const float* Whh_b = (const float*)d_in[5];
    const float* b_b   = (const float*)d_in[6];
    const float* Wa    = (const float*)d_in[7];
    const float* ba    = (const float*)d_in[8];
    const float* Wao   = (const float*)d_in[9];
    const float* bao   = (const float*)d_in[10];
    const float* Wd    = (const float*)d_in[11];
    const float* bd    = (const float*)d_in[12];
    const float* Wdo   = (const float*)d_in[13];
    const float* bdo   = (const float*)d_in[14];
    float* out = (float*)d_out;

    char* ws = (char*)d_ws;
    size_t off = 0;
    __hip_bfloat16* arc_f = (__hip_bfloat16*)(ws + off); off += (size_t)kE * kH * 2;  // 32 MB
    __hip_bfloat16* arc_b = (__hip_bfloat16*)(ws + off); off += (size_t)kE * kH * 2;  // 32 MB
    ull* hpay = (ull*)(ws + off); off += (size_t)2 * 2 * 4 * kH * 8;                  // 64 KB
    ull* zpay = (ull*)(ws + off); off += (size_t)2 * 2 * 32 * 256 * 8;                // 256 KB

    if (ws_size < off) {
        hipLaunchKernelGGL(k_zero, dim3((kE + 255) / 256), dim3(256), 0, stream, out);
        return;
    }

    hipLaunchKernelGGL(k_init, dim3(128), dim3(256), 0, stream, out, bdo, hpay, zpay);
    hipLaunchKernelGGL(k_recur, dim3(64), dim3(256), 0, stream,
                       edges, Wih_f, Whh_f, b_f, Wih_b, Whh_b, b_b,
                       Wa, ba, Wao, bao, arc_f, arc_b, hpay, zpay);
    hipLaunchKernelGGL(k_dec, dim3(kE / 128, kL / 128), dim3(256), 0, stream,
                       arc_f, arc_b, Wd, bd, Wdo, out);
}

// Round 4
// 47396.893 us; speedup vs baseline: 2.6159x; 1.0445x over previous
//
#include <hip/hip_runtime.h>
#include <hip/hip_bf16.h>

// Problem constants
constexpr int kN = 8192;
constexpr int kF = 256;
constexpr int kH = 512;
constexpr int kL = 512;
constexpr int kE = kN * 4;           // 32768 edges

using ull = unsigned long long;

__device__ __forceinline__ float sigm(float x) { return 1.f / (1.f + __expf(-x)); }

__device__ __forceinline__ float4 ld_bf4(const __hip_bfloat16* p) {
    uint2 u = *(const uint2*)p;
    float4 r;
    r.x = __uint_as_float(u.x << 16);
    r.y = __uint_as_float(u.x & 0xffff0000u);
    r.z = __uint_as_float(u.y << 16);
    r.w = __uint_as_float(u.y & 0xffff0000u);
    return r;
}

// stamped 8-byte pair: low = float bits, high = stamp (step+1)
__device__ __forceinline__ void st_pair(ull* p, float v, unsigned stamp) {
    ull u = ((ull)stamp << 32) | (ull)__float_as_uint(v);
    __hip_atomic_store(p, u, __ATOMIC_RELAXED, __HIP_MEMORY_SCOPE_AGENT);
}
__device__ __forceinline__ ull ld_raw(const ull* p) {
    return __hip_atomic_load(p, __ATOMIC_RELAXED, __HIP_MEMORY_SCOPE_AGENT);
}

// ---------------------------------------------------------------------------
__global__ void k_init(float* __restrict__ out, const float* __restrict__ bdo,
                       ull* __restrict__ hpay, ull* __restrict__ zpay) {
    int idx = blockIdx.x * 256 + threadIdx.x;
    if (idx < kE) out[idx] = bdo[0];
    if (idx < 2 * 2 * 4 * kH) hpay[idx] = 0ull;
    if (idx < 2 * 2 * 32 * 256) zpay[idx] = 0ull;
}

__global__ void k_zero(float* __restrict__ out) {
    int idx = blockIdx.x * 256 + threadIdx.x;
    if (idx < kE) out[idx] = 0.f;
}

// ---------------------------------------------------------------------------
// Recurrent kernel: 64 persistent blocks (32/dir), 256 threads each.
// Block b owns h-dims [b*16, b*16+16) -> 64 gate rows (Whh slice in VGPRs).
// Cross-block exchange: stamped 64-bit pairs, relaxed agent atomics only.
// Resolve loops use BATCHED sweeps: all unresolved entries re-issued in
// flight each sweep (one MALL round trip per sweep, not per entry).
// ---------------------------------------------------------------------------
__global__ __launch_bounds__(256, 1) void k_recur(
    const float* __restrict__ edges,
    const float* __restrict__ Wih_f, const float* __restrict__ Whh_f, const float* __restrict__ b_f,
    const float* __restrict__ Wih_b, const float* __restrict__ Whh_b, const float* __restrict__ b_b,
    const float* __restrict__ Wa, const float* __restrict__ ba,
    const float* __restrict__ Wao, const float* __restrict__ bao,
    __hip_bfloat16* __restrict__ arc_f, __hip_bfloat16* __restrict__ arc_b,
    ull* __restrict__ hpay, ull* __restrict__ zpay) {

    const int blk = blockIdx.x;
    const int dir = blk >> 5;
    const int b   = blk & 31;
    const float* __restrict__ Whh = dir ? Whh_b : Whh_f;
    const float* __restrict__ Wih = dir ? Wih_b : Wih_f;
    const float* __restrict__ bia = dir ? b_b  : b_f;
    __hip_bfloat16* __restrict__ arc = dir ? arc_b : arc_f;
    const int tid = threadIdx.x;

    // matvec roles: 64 gate rows x 4-way K split
    const int jl = tid >> 2, ks = tid & 3;
    const int Jg = (jl >> 4) * kH + b * 16 + (jl & 15);
    // gate / xproj / z roles: wave = arc, lane = gate row (or attention unit)
    const int d_g = tid >> 6, jl2 = tid & 63;
    const int Jg2 = (jl2 >> 4) * kH + b * 16 + (jl2 & 15);
    const int a_id = jl2;

    float w[128];
    {
        const float* wr = Whh + (size_t)Jg * kH + ks * 128;
        #pragma unroll
        for (int kk = 0; kk < 128; kk++) w[kk] = wr[kk];
    }
    float wih[64];
    {
        const float* wr = Wih + (size_t)Jg2 * kF + d_g * 64;
        #pragma unroll
        for (int kk = 0; kk < 64; kk++) wih[kk] = wr[kk];
    }
    const float biasR = bia[Jg2];
    const float baR   = ba[a_id];
    const float WaoR  = Wao[a_id];
    const float baoR  = bao[0];
    const float wax0  = Wa[(size_t)a_id * 515 + 512];
    const float wax1  = Wa[(size_t)a_id * 515 + 513];
    const float wax2  = Wa[(size_t)a_id * 515 + 514];

    // hprev padded: 4 chunks of 132 floats (banks offset 4 per chunk -> no conflict)
    __shared__ __align__(16) float hprev_p[4 * 132];
    __shared__ float Mh[4][64];
    __shared__ float cring[4][16];
    __shared__ float gl[4][64];
    __shared__ float harcl[4][16];
    __shared__ float carcl[4][16];
    __shared__ float logit_l[4];
    __shared__ float WaS[64][17];
    __shared__ __align__(16) float x_s[4][256];
    __shared__ float xpart[4][4][64];

    for (int l2 = tid; l2 < 4 * 132; l2 += 256) hprev_p[l2] = 0.f;
    Mh[tid >> 6][tid & 63] = 0.f;
    if (tid < 64) cring[tid >> 4][tid & 15] = 0.f;
    for (int l2 = tid; l2 < 1024; l2 += 256)
        WaS[l2 >> 4][l2 & 15] = Wa[(size_t)(l2 >> 4) * 515 + b * 16 + (l2 & 15)];
    __syncthreads();

// issue the edge-row load for node nn (block-uniform)
#define XLOAD(nn, XV) do {                                                    \
        int row_;                                                             \
        if (dir == 0) row_ = (nn) * 4 + d_g;                                  \
        else { row_ = ((nn) + 1 + d_g) * 4 + d_g;                             \
               if (row_ > kE - 1) row_ = kE - 1; }                            \
        XV = *(const float4*)(edges + (size_t)row_ * kF + 4 * jl2);           \
    } while (0)

// finish xproj from a prefetched edge vector
#define XFIN(XV, XPOUT, ZXOUT) do {                                           \
        *(float4*)(&x_s[d_g][4 * jl2]) = XV;                                  \
        __syncthreads();                                                      \
        float p0_ = 0.f, p1_ = 0.f, p2_ = 0.f, p3_ = 0.f;                     \
        _Pragma("unroll")                                                     \
        for (int k4_ = 0; k4_ < 16; k4_++) {                                  \
            float4 a0_ = *(const float4*)&x_s[0][d_g * 64 + k4_ * 4];         \
            float4 a1_ = *(const float4*)&x_s[1][d_g * 64 + k4_ * 4];         \
            float4 a2_ = *(const float4*)&x_s[2][d_g * 64 + k4_ * 4];         \
            float4 a3_ = *(const float4*)&x_s[3][d_g * 64 + k4_ * 4];         \
            float w0_ = wih[k4_*4], w1_ = wih[k4_*4+1];                       \
            float w2_ = wih[k4_*4+2], w3_ = wih[k4_*4+3];                     \
            p0_ += w0_*a0_.x + w1_*a0_.y + w2_*a0_.z + w3_*a0_.w;             \
            p1_ += w0_*a1_.x + w1_*a1_.y + w2_*a1_.z + w3_*a1_.w;             \
            p2_ += w0_*a2_.x + w1_*a2_.y + w2_*a2_.z + w3_*a2_.w;             \
            p3_ += w0_*a3_.x + w1_*a3_.y + w2_*a3_.z + w3_*a3_.w;             \
        }                                                                     \
        xpart[d_g][0][jl2] = p0_; xpart[d_g][1][jl2] = p1_;                   \
        xpart[d_g][2][jl2] = p2_; xpart[d_g][3][jl2] = p3_;                   \
        __syncthreads();                                                      \
        XPOUT = biasR + xpart[0][d_g][jl2] + xpart[1][d_g][jl2]               \
                      + xpart[2][d_g][jl2] + xpart[3][d_g][jl2];              \
        ZXOUT = baR + wax0 * x_s[d_g][0] + wax1 * x_s[d_g][1]                 \
                    + wax2 * x_s[d_g][2];                                     \
    } while (0)

    const int i0 = dir ? kN - 1 : 0;
    float xp, zxv;
    {
        float4 xv0;
        XLOAD(i0, xv0);
        XFIN(xv0, xp, zxv);
    }

    for (int t = 0; t < kN; t++) {
        const int i = dir ? kN - 1 - t : t;
        const unsigned stamp = (unsigned)(t + 1);
        const int par = t & 1;

        // ---- prefetch next step's edge row (latency overlaps phases A/B) ----
        float4 xv_n;
        {
            const int nn = (t + 1 < kN) ? (dir ? i - 1 : i + 1) : i;
            XLOAD(nn, xv_n);
        }

        // ---- A: M[iprev] = hprev . Whh^T (own 64 rows) ----
        float acc = 0.f;
        {
            const float* hp = &hprev_p[ks * 132];
            #pragma unroll
            for (int kk = 0; kk < 128; kk += 4) {
                float4 hv = *(const float4*)(hp + kk);
                acc += w[kk] * hv.x + w[kk+1] * hv.y + w[kk+2] * hv.z + w[kk+3] * hv.w;
            }
        }
        acc += __shfl_xor(acc, 1);
        acc += __shfl_xor(acc, 2);
        const int iprev = dir ? i + 1 : i - 1;
        if (ks == 0) Mh[iprev & 3][jl] = acc;
        __syncthreads();

        // ---- B: gates ----
        {
            const int p = dir ? i + 1 + d_g : i - 1 - d_g;
            gl[d_g][jl2] = xp + Mh[p & 3][jl2];
        }
        __syncthreads();
        if (tid < 64) {
            const int d3 = tid >> 4, s3 = tid & 15;
            const int pp = dir ? i + 1 + d3 : i - 1 - d3;
            const bool v3 = dir ? (pp < kN) : (pp >= 0);
            float gi = gl[d3][s3],      gf = gl[d3][16 + s3];
            float gg = gl[d3][32 + s3], go = gl[d3][48 + s3];
            float cp = cring[pp & 3][s3];
            float c = sigm(gf) * cp + sigm(gi) * tanhf(gg);
            float h = sigm(go) * tanhf(c);
            float hm = v3 ? h : 0.f, cm = v3 ? c : 0.f;
            harcl[d3][s3] = hm; carcl[d3][s3] = cm;
            arc[((size_t)i * 4 + d3) * kH + b * 16 + s3] = __float2bfloat16(hm);
            st_pair(hpay + (((dir * 2 + par) * 4 + d3) << 9) + b * 16 + s3, hm, stamp);
        }
        __syncthreads();
        // z partials over own 16 h-dims, publish
        {
            float zp = 0.f;
            #pragma unroll
            for (int ss = 0; ss < 16; ss++) zp += WaS[a_id][ss] * harcl[d_g][ss];
            st_pair(zpay + (((dir * 2 + par) * 32 + b) << 8) + tid, zp, stamp);
        }

        // ---- C: next step's input projection (overlaps publish latency) ----
        float xp_n, zx_n;
        XFIN(xv_n, xp_n, zx_n);

        // ---- E: batched stamped loads (z + h) ----
        const ull* zb = zpay + (((size_t)(dir * 2 + par) * 32) << 8) + tid;
        ull zv_[32];
        #pragma unroll
        for (int bb = 0; bb < 32; bb++) zv_[bb] = ld_raw(zb + ((size_t)bb << 8));
        const ull* hb = hpay + (((size_t)(dir * 2 + par) * 4) << 9);
        ull hv_[8];
        #pragma unroll
        for (int dd = 0; dd < 4; dd++) {
            hv_[2*dd]   = ld_raw(hb + (dd << 9) + 2 * tid);
            hv_[2*dd+1] = ld_raw(hb + (dd << 9) + 2 * tid + 1);
        }

        // resolve z: batched sweeps (all unresolved re-issued in flight)
        for (;;) {
            bool ok = true;
            #pragma unroll
            for (int bb = 0; bb < 32; bb++)
                ok &= ((unsigned)(zv_[bb] >> 32) == stamp);
            if (ok) break;
            #pragma unroll
            for (int bb = 0; bb < 32; bb++)
                if ((unsigned)(zv_[bb] >> 32) != stamp)
                    zv_[bb] = ld_raw(zb + ((size_t)bb << 8));
        }
        float zsum = 0.f;
        #pragma unroll
        for (int bb = 0; bb < 32; bb++) zsum += __uint_as_float((unsigned)zv_[bb]);

        // resolve h: batched sweeps
        for (;;) {
            bool ok = true;
            #pragma unroll
            for (int q = 0; q < 8; q++)
                ok &= ((unsigned)(hv_[q] >> 32) == stamp);
            if (ok) break;
            #pragma unroll
            for (int dd = 0; dd < 4; dd++) {
                if ((unsigned)(hv_[2*dd]   >> 32) != stamp) hv_[2*dd]   = ld_raw(hb + (dd << 9) + 2 * tid);
                if ((unsigned)(hv_[2*dd+1] >> 32) != stamp) hv_[2*dd+1] = ld_raw(hb + (dd << 9) + 2 * tid + 1);
            }
        }

        float zv = fmaxf(zsum + zxv, 0.f);
        float lv = WaoR * zv;
        #pragma unroll
        for (int o2 = 1; o2 < 64; o2 <<= 1) lv += __shfl_xor(lv, o2);
        if (a_id == 0) {
            const int pp = dir ? i + 1 + d_g : i - 1 - d_g;
            const bool v3 = dir ? (pp < kN) : (pp >= 0);
            logit_l[d_g] = v3 ? tanhf(lv + baoR) : -1e9f;
        }
        __syncthreads();

        float l0 = logit_l[0], l1 = logit_l[1], l2 = logit_l[2], l3 = logit_l[3];
        float mx = fmaxf(fmaxf(l0, l1), fmaxf(l2, l3));
        float e0 = __expf(l0 - mx), e1 = __expf(l1 - mx);
        float e2 = __expf(l2 - mx), e3 = __expf(l3 - mx);
        float inv = 1.f / (e0 + e1 + e2 + e3);
        float wg[4] = { e0 * inv, e1 * inv, e2 * inv, e3 * inv };

        float hn0 = 0.f, hn1 = 0.f;
        #pragma unroll
        for (int dd = 0; dd < 4; dd++) {
            hn0 += wg[dd] * __uint_as_float((unsigned)hv_[2*dd]);
            hn1 += wg[dd] * __uint_as_float((unsigned)hv_[2*dd+1]);
        }
        {
            const int g = 2 * tid;
            const int ch = g >> 7, wi = g & 127;
            hprev_p[ch * 132 + wi]     = hn0;
            hprev_p[ch * 132 + wi + 1] = hn1;
        }
        if (tid < 16) {
            float cn = wg[0] * carcl[0][tid] + wg[1] * carcl[1][tid]
                     + wg[2] * carcl[2][tid] + wg[3] * carcl[3][tid];
            cring[i & 3][tid] = cn;
        }
        __syncthreads();

        xp = xp_n; zxv = zx_n;
    }
#undef XLOAD
#undef XFIN
}

// ---------------------------------------------------------------------------
// decoder: out[e] += sum_l Wdo[l] * relu(bd[l] + sum_k Wd[l,k] feat[e,k])
// ---------------------------------------------------------------------------
__global__ __launch_bounds__(256) void k_dec(
    const __hip_bfloat16* __restrict__ arc_f, const __hip_bfloat16* __restrict__ arc_b,
    const float* __restrict__ Wd, const float* __restrict__ bd,
    const float* __restrict__ Wdo, float* __restrict__ out) {
    const int e0 = blockIdx.x * 128;
    const int l0 = blockIdx.y * 128;
    __shared__ __align__(16) float As[8][128];
    __shared__ __align__(16) float Bs[8][128];
    const int tid = threadIdx.x;
    const int tx = tid & 15, ty = tid >> 4;
    const int lr = tid & 127, kq = tid >> 7;

    const int e = e0 + lr;
    const int j = e >> 2, d = e & 3;
    const int jb = j - 1 - d;
    const __hip_bfloat16* frow  = arc_f + (size_t)e * kH;
    const __hip_bfloat16* brow2 = (jb >= 0) ? (arc_b + ((size_t)jb * 4 + d) * kH) : nullptr;
    const float* wrow = Wd + (size_t)(l0 + lr) * (2 * kH);

    float acc[8][8] = {};
    for (int k0 = 0; k0 < 2 * kH; k0 += 8) {
        const int kk = k0 + kq * 4;
        float4 av4;
        if (kk < kH) av4 = ld_bf4(frow + kk);
        else if (brow2) av4 = ld_bf4(brow2 + (kk - kH));
        else av4 = make_float4(0.f, 0.f, 0.f, 0.f);
        float4 bv4 = *(const float4*)(wrow + kk);
        __syncthreads();
        As[kq*4+0][lr] = av4.x; As[kq*4+1][lr] = av4.y;
        As[kq*4+2][lr] = av4.z; As[kq*4+3][lr] = av4.w;
        Bs[kq*4+0][lr] = bv4.x; Bs[kq*4+1][lr] = bv4.y;
        Bs[kq*4+2][lr] = bv4.z; Bs[kq*4+3][lr] = bv4.w;
        __syncthreads();
        #pragma unroll
        for (int kt = 0; kt < 8; kt++) {
            __align__(16) float a0[8], b0[8];
            *(float4*)&a0[0] = *(const float4*)&As[kt][ty*8];
            *(float4*)&a0[4] = *(const float4*)&As[kt][ty*8+4];
            *(float4*)&b0[0] = *(const float4*)&Bs[kt][tx*8];
            *(float4*)&b0[4] = *(const float4*)&Bs[kt][tx*8+4];
            #pragma unroll
            for (int mi = 0; mi < 8; mi++)
                #pragma unroll
                for (int ni = 0; ni < 8; ni++)
                    acc[mi][ni] += a0[mi] * b0[ni];
        }
    }
    #pragma unroll
    for (int mi = 0; mi < 8; mi++) {
        float sacc = 0.f;
        #pragma unroll
        for (int ni = 0; ni < 8; ni++) {
            int l = l0 + tx * 8 + ni;
            sacc += Wdo[l] * fmaxf(acc[mi][ni] + bd[l], 0.f);
        }
        sacc += __shfl_xor(sacc, 1);
        sacc += __shfl_xor(sacc, 2);
        sacc += __shfl_xor(sacc, 4);
        sacc += __shfl_xor(sacc, 8);
        if (tx == 0) atomicAdd(out + e0 + ty * 8 + mi, sacc);
    }
}

// ---------------------------------------------------------------------------
extern "C" void kernel_launch(void* const* d_in, const int* in_sizes, int n_in,
                              void* d_out, int out_size, void* d_ws, size_t ws_size,
                              hipStream_t stream) {
    const float* edges = (const float*)d_in[0];
    const float* Wih_f = (const float*)d_in[1];
    const float* Whh_f = (const float*)d_in[2];
    const float* b_f   = (const float*)d_in[3];
    const float* Wih_b = (const float*)d_in[4];
    const float* Whh_b = (const float*)d_in[5];
    const float* b_b   = (const float*)d_in[6];
    const float* Wa    = (const float*)d_in[7];
    const float* ba    = (const float*)d_in[8];
    const float* Wao   = (const float*)d_in[9];
    const float* bao   = (const float*)d_in[10];
    const float* Wd    = (const float*)d_in[11];
    const float* bd    = (const float*)d_in[12];
    const float* Wdo   = (const float*)d_in[13];
    const float* bdo   = (const float*)d_in[14];
    float* out = (float*)d_out;

    char* ws = (char*)d_ws;
    size_t off = 0;
    __hip_bfloat16* arc_f = (__hip_bfloat16*)(ws + off); off += (size_t)kE * kH * 2;  // 32 MB
    __hip_bfloat16* arc_b = (__hip_bfloat16*)(ws + off); off += (size_t)kE * kH * 2;  // 32 MB
    ull* hpay = (ull*)(ws + off); off += (size_t)2 * 2 * 4 * kH * 8;                  // 64 KB
    ull* zpay = (ull*)(ws + off); off += (size_t)2 * 2 * 32 * 256 * 8;                // 256 KB

    if (ws_size < off) {
        hipLaunchKernelGGL(k_zero, dim3((kE + 255) / 256), dim3(256), 0, stream, out);
        return;
    }

    hipLaunchKernelGGL(k_init, dim3(128), dim3(256), 0, stream, out, bdo, hpay, zpay);
    hipLaunchKernelGGL(k_recur, dim3(64), dim3(256), 0, stream,
                       edges, Wih_f, Whh_f, b_f, Wih_b, Whh_b, b_b,
                       Wa, ba, Wao, bao, arc_f, arc_b, hpay, zpay);
    hipLaunchKernelGGL(k_dec, dim3(kE / 128, kL / 128), dim3(256), 0, stream,
                       arc_f, arc_b, Wd, bd, Wdo, out);
}

// Round 5
// 45942.349 us; speedup vs baseline: 2.6988x; 1.0317x over previous
//
#include <hip/hip_runtime.h>
#include <hip/hip_bf16.h>

// Problem constants
constexpr int kN = 8192;
constexpr int kF = 256;
constexpr int kH = 512;
constexpr int kL = 512;
constexpr int kE = kN * 4;           // 32768 edges

using ull = unsigned long long;

__device__ __forceinline__ float sigm(float x) { return 1.f / (1.f + __expf(-x)); }

__device__ __forceinline__ float4 ld_bf4(const __hip_bfloat16* p) {
    uint2 u = *(const uint2*)p;
    float4 r;
    r.x = __uint_as_float(u.x << 16);
    r.y = __uint_as_float(u.x & 0xffff0000u);
    r.z = __uint_as_float(u.y << 16);
    r.w = __uint_as_float(u.y & 0xffff0000u);
    return r;
}

// stamped 8-byte pair: low = float bits, high = stamp (step+1)
__device__ __forceinline__ void st_pair(ull* p, float v, unsigned stamp) {
    ull u = ((ull)stamp << 32) | (ull)__float_as_uint(v);
    __hip_atomic_store(p, u, __ATOMIC_RELAXED, __HIP_MEMORY_SCOPE_AGENT);
}
__device__ __forceinline__ ull ld_raw(const ull* p) {
    return __hip_atomic_load(p, __ATOMIC_RELAXED, __HIP_MEMORY_SCOPE_AGENT);
}

// ---------------------------------------------------------------------------
__global__ void k_init(float* __restrict__ out, const float* __restrict__ bdo,
                       ull* __restrict__ hpay, ull* __restrict__ zpay,
                       int* __restrict__ claims) {
    int idx = blockIdx.x * 256 + threadIdx.x;
    if (idx < kE) out[idx] = bdo[0];
    if (idx < 2 * 2 * 4 * kH) hpay[idx] = 0ull;
    if (idx < 2 * 2 * 32 * 256) zpay[idx] = 0ull;
    if (idx < 2) claims[idx] = 0;
}

__global__ void k_zero(float* __restrict__ out) {
    int idx = blockIdx.x * 256 + threadIdx.x;
    if (idx < kE) out[idx] = 0.f;
}

// ---------------------------------------------------------------------------
// Recurrent kernel: 512 candidate blocks; 32 working blocks per direction,
// claimed by XCD so each direction's exchange stays inside ONE XCD L2
// (XCD0 -> forward, XCD1 -> backward; other XCDs are late fallback).
// Block b owns h-dims [b*16, b*16+16) -> 64 gate rows (Whh slice in VGPRs).
// Cross-block exchange: stamped 64-bit pairs, relaxed agent atomics only.
// ---------------------------------------------------------------------------
__global__ __launch_bounds__(256, 1) void k_recur(
    const float* __restrict__ edges,
    const float* __restrict__ Wih_f, const float* __restrict__ Whh_f, const float* __restrict__ b_f,
    const float* __restrict__ Wih_b, const float* __restrict__ Whh_b, const float* __restrict__ b_b,
    const float* __restrict__ Wa, const float* __restrict__ ba,
    const float* __restrict__ Wao, const float* __restrict__ bao,
    __hip_bfloat16* __restrict__ arc_f, __hip_bfloat16* __restrict__ arc_b,
    ull* __restrict__ hpay, ull* __restrict__ zpay, int* __restrict__ claims) {

    // ---- XCD-affine slot claim ----
    __shared__ int s_slot;
    if (threadIdx.x == 0) {
        // s_getreg(HW_REG_XCC_ID): simm16 = (size-1)<<11 | offset<<6 | id(20)
        unsigned xcc = (unsigned)__builtin_amdgcn_s_getreg((31 << 11) | (0 << 6) | 20) & 15u;
        int slot = -1;
        if (xcc <= 1) {
            int c = atomicAdd(&claims[xcc], 1);
            if (c < 32) slot = (int)xcc * 32 + c;
        } else {
            // wrong XCD: wait ~100us, then fill any unfilled slots (robust fallback)
            for (int sl = 0; sl < 64; sl++) __builtin_amdgcn_s_sleep(64);
            for (int dd = 0; dd < 2 && slot < 0; dd++) {
                if (__hip_atomic_load(&claims[dd], __ATOMIC_RELAXED,
                                      __HIP_MEMORY_SCOPE_AGENT) < 32) {
                    int c = atomicAdd(&claims[dd], 1);
                    if (c < 32) slot = dd * 32 + c;
                }
            }
        }
        s_slot = slot;
    }
    __syncthreads();
    const int slot = s_slot;
    if (slot < 0) return;
    const int dir = slot >> 5;
    const int b   = slot & 31;

    const float* __restrict__ Whh = dir ? Whh_b : Whh_f;
    const float* __restrict__ Wih = dir ? Wih_b : Wih_f;
    const float* __restrict__ bia = dir ? b_b  : b_f;
    __hip_bfloat16* __restrict__ arc = dir ? arc_b : arc_f;
    const int tid = threadIdx.x;

    // matvec roles: 64 gate rows x 4-way K split
    const int jl = tid >> 2, ks = tid & 3;
    const int Jg = (jl >> 4) * kH + b * 16 + (jl & 15);
    // gate / xproj / z roles: wave = arc, lane = gate row (or attention unit)
    const int d_g = tid >> 6, jl2 = tid & 63;
    const int Jg2 = (jl2 >> 4) * kH + b * 16 + (jl2 & 15);
    const int a_id = jl2;

    float w[128];
    {
        const float* wr = Whh + (size_t)Jg * kH + ks * 128;
        #pragma unroll
        for (int kk = 0; kk < 128; kk++) w[kk] = wr[kk];
    }
    float wih[64];
    {
        const float* wr = Wih + (size_t)Jg2 * kF + d_g * 64;
        #pragma unroll
        for (int kk = 0; kk < 64; kk++) wih[kk] = wr[kk];
    }
    const float biasR = bia[Jg2];
    const float baR   = ba[a_id];
    const float WaoR  = Wao[a_id];
    const float baoR  = bao[0];
    const float wax0  = Wa[(size_t)a_id * 515 + 512];
    const float wax1  = Wa[(size_t)a_id * 515 + 513];
    const float wax2  = Wa[(size_t)a_id * 515 + 514];

    // hprev padded: 4 chunks of 132 floats (banks offset 4 per chunk -> no conflict)
    __shared__ __align__(16) float hprev_p[4 * 132];
    __shared__ float Mh[4][64];
    __shared__ float cring[4][16];
    __shared__ float gl[4][64];
    __shared__ float harcl[4][16];
    __shared__ float carcl[4][16];
    __shared__ float logit_l[4];
    __shared__ float WaS[64][17];
    __shared__ __align__(16) float x_s[4][256];
    __shared__ float xpart[4][4][64];

    for (int l2 = tid; l2 < 4 * 132; l2 += 256) hprev_p[l2] = 0.f;
    Mh[tid >> 6][tid & 63] = 0.f;
    if (tid < 64) cring[tid >> 4][tid & 15] = 0.f;
    for (int l2 = tid; l2 < 1024; l2 += 256)
        WaS[l2 >> 4][l2 & 15] = Wa[(size_t)(l2 >> 4) * 515 + b * 16 + (l2 & 15)];
    __syncthreads();

// issue the edge-row load for node nn (block-uniform)
#define XLOAD(nn, XV) do {                                                    \
        int row_;                                                             \
        if (dir == 0) row_ = (nn) * 4 + d_g;                                  \
        else { row_ = ((nn) + 1 + d_g) * 4 + d_g;                             \
               if (row_ > kE - 1) row_ = kE - 1; }                            \
        XV = *(const float4*)(edges + (size_t)row_ * kF + 4 * jl2);           \
    } while (0)

// finish xproj from a prefetched edge vector
#define XFIN(XV, XPOUT, ZXOUT) do {                                           \
        *(float4*)(&x_s[d_g][4 * jl2]) = XV;                                  \
        __syncthreads();                                                      \
        float p0_ = 0.f, p1_ = 0.f, p2_ = 0.f, p3_ = 0.f;                     \
        _Pragma("unroll")                                                     \
        for (int k4_ = 0; k4_ < 16; k4_++) {                                  \
            float4 a0_ = *(const float4*)&x_s[0][d_g * 64 + k4_ * 4];         \
            float4 a1_ = *(const float4*)&x_s[1][d_g * 64 + k4_ * 4];         \
            float4 a2_ = *(const float4*)&x_s[2][d_g * 64 + k4_ * 4];         \
            float4 a3_ = *(const float4*)&x_s[3][d_g * 64 + k4_ * 4];         \
            float w0_ = wih[k4_*4], w1_ = wih[k4_*4+1];                       \
            float w2_ = wih[k4_*4+2], w3_ = wih[k4_*4+3];                     \
            p0_ += w0_*a0_.x + w1_*a0_.y + w2_*a0_.z + w3_*a0_.w;             \
            p1_ += w0_*a1_.x + w1_*a1_.y + w2_*a1_.z + w3_*a1_.w;             \
            p2_ += w0_*a2_.x + w1_*a2_.y + w2_*a2_.z + w3_*a2_.w;             \
            p3_ += w0_*a3_.x + w1_*a3_.y + w2_*a3_.z + w3_*a3_.w;             \
        }                                                                     \
        xpart[d_g][0][jl2] = p0_; xpart[d_g][1][jl2] = p1_;                   \
        xpart[d_g][2][jl2] = p2_; xpart[d_g][3][jl2] = p3_;                   \
        __syncthreads();                                                      \
        XPOUT = biasR + xpart[0][d_g][jl2] + xpart[1][d_g][jl2]               \
                      + xpart[2][d_g][jl2] + xpart[3][d_g][jl2];              \
        ZXOUT = baR + wax0 * x_s[d_g][0] + wax1 * x_s[d_g][1]                 \
                    + wax2 * x_s[d_g][2];                                     \
    } while (0)

    const int i0 = dir ? kN - 1 : 0;
    float xp, zxv;
    {
        float4 xv0;
        XLOAD(i0, xv0);
        XFIN(xv0, xp, zxv);
    }

    for (int t = 0; t < kN; t++) {
        const int i = dir ? kN - 1 - t : t;
        const unsigned stamp = (unsigned)(t + 1);
        const int par = t & 1;

        // ---- prefetch next step's edge row (latency overlaps phases A/B) ----
        float4 xv_n;
        {
            const int nn = (t + 1 < kN) ? (dir ? i - 1 : i + 1) : i;
            XLOAD(nn, xv_n);
        }

        // ---- A: M[iprev] = hprev . Whh^T (own 64 rows) ----
        float acc = 0.f;
        {
            const float* hp = &hprev_p[ks * 132];
            #pragma unroll
            for (int kk = 0; kk < 128; kk += 4) {
                float4 hv = *(const float4*)(hp + kk);
                acc += w[kk] * hv.x + w[kk+1] * hv.y + w[kk+2] * hv.z + w[kk+3] * hv.w;
            }
        }
        acc += __shfl_xor(acc, 1);
        acc += __shfl_xor(acc, 2);
        const int iprev = dir ? i + 1 : i - 1;
        if (ks == 0) Mh[iprev & 3][jl] = acc;
        __syncthreads();

        // ---- B: gates ----
        {
            const int p = dir ? i + 1 + d_g : i - 1 - d_g;
            gl[d_g][jl2] = xp + Mh[p & 3][jl2];
        }
        __syncthreads();
        if (tid < 64) {
            const int d3 = tid >> 4, s3 = tid & 15;
            const int pp = dir ? i + 1 + d3 : i - 1 - d3;
            const bool v3 = dir ? (pp < kN) : (pp >= 0);
            float gi = gl[d3][s3],      gf = gl[d3][16 + s3];
            float gg = gl[d3][32 + s3], go = gl[d3][48 + s3];
            float cp = cring[pp & 3][s3];
            float c = sigm(gf) * cp + sigm(gi) * tanhf(gg);
            float h = sigm(go) * tanhf(c);
            float hm = v3 ? h : 0.f, cm = v3 ? c : 0.f;
            harcl[d3][s3] = hm; carcl[d3][s3] = cm;
            arc[((size_t)i * 4 + d3) * kH + b * 16 + s3] = __float2bfloat16(hm);
            st_pair(hpay + (((dir * 2 + par) * 4 + d3) << 9) + b * 16 + s3, hm, stamp);
        }
        __syncthreads();
        // z partials over own 16 h-dims, publish
        {
            float zp = 0.f;
            #pragma unroll
            for (int ss = 0; ss < 16; ss++) zp += WaS[a_id][ss] * harcl[d_g][ss];
            st_pair(zpay + (((dir * 2 + par) * 32 + b) << 8) + tid, zp, stamp);
        }

        // ---- C: next step's input projection (overlaps publish latency) ----
        float xp_n, zx_n;
        XFIN(xv_n, xp_n, zx_n);

        // ---- E: batched stamped loads (z + h) ----
        const ull* zb = zpay + (((size_t)(dir * 2 + par) * 32) << 8) + tid;
        ull zv_[32];
        #pragma unroll
        for (int bb = 0; bb < 32; bb++) zv_[bb] = ld_raw(zb + ((size_t)bb << 8));
        const ull* hb = hpay + (((size_t)(dir * 2 + par) * 4) << 9);
        ull hv_[8];
        #pragma unroll
        for (int dd = 0; dd < 4; dd++) {
            hv_[2*dd]   = ld_raw(hb + (dd << 9) + 2 * tid);
            hv_[2*dd+1] = ld_raw(hb + (dd << 9) + 2 * tid + 1);
        }

        // resolve z: batched sweeps (all unresolved re-issued in flight)
        for (;;) {
            bool ok = true;
            #pragma unroll
            for (int bb = 0; bb < 32; bb++)
                ok &= ((unsigned)(zv_[bb] >> 32) == stamp);
            if (ok) break;
            #pragma unroll
            for (int bb = 0; bb < 32; bb++)
                if ((unsigned)(zv_[bb] >> 32) != stamp)
                    zv_[bb] = ld_raw(zb + ((size_t)bb << 8));
        }
        float zsum = 0.f;
        #pragma unroll
        for (int bb = 0; bb < 32; bb++) zsum += __uint_as_float((unsigned)zv_[bb]);

        // resolve h: batched sweeps
        for (;;) {
            bool ok = true;
            #pragma unroll
            for (int q = 0; q < 8; q++)
                ok &= ((unsigned)(hv_[q] >> 32) == stamp);
            if (ok) break;
            #pragma unroll
            for (int dd = 0; dd < 4; dd++) {
                if ((unsigned)(hv_[2*dd]   >> 32) != stamp) hv_[2*dd]   = ld_raw(hb + (dd << 9) + 2 * tid);
                if ((unsigned)(hv_[2*dd+1] >> 32) != stamp) hv_[2*dd+1] = ld_raw(hb + (dd << 9) + 2 * tid + 1);
            }
        }

        float zv = fmaxf(zsum + zxv, 0.f);
        float lv = WaoR * zv;
        #pragma unroll
        for (int o2 = 1; o2 < 64; o2 <<= 1) lv += __shfl_xor(lv, o2);
        if (a_id == 0) {
            const int pp = dir ? i + 1 + d_g : i - 1 - d_g;
            const bool v3 = dir ? (pp < kN) : (pp >= 0);
            logit_l[d_g] = v3 ? tanhf(lv + baoR) : -1e9f;
        }
        __syncthreads();

        float l0 = logit_l[0], l1 = logit_l[1], l2 = logit_l[2], l3 = logit_l[3];
        float mx = fmaxf(fmaxf(l0, l1), fmaxf(l2, l3));
        float e0 = __expf(l0 - mx), e1 = __expf(l1 - mx);
        float e2 = __expf(l2 - mx), e3 = __expf(l3 - mx);
        float inv = 1.f / (e0 + e1 + e2 + e3);
        float wg[4] = { e0 * inv, e1 * inv, e2 * inv, e3 * inv };

        float hn0 = 0.f, hn1 = 0.f;
        #pragma unroll
        for (int dd = 0; dd < 4; dd++) {
            hn0 += wg[dd] * __uint_as_float((unsigned)hv_[2*dd]);
            hn1 += wg[dd] * __uint_as_float((unsigned)hv_[2*dd+1]);
        }
        {
            const int g = 2 * tid;
            const int ch = g >> 7, wi = g & 127;
            hprev_p[ch * 132 + wi]     = hn0;
            hprev_p[ch * 132 + wi + 1] = hn1;
        }
        if (tid < 16) {
            float cn = wg[0] * carcl[0][tid] + wg[1] * carcl[1][tid]
                     + wg[2] * carcl[2][tid] + wg[3] * carcl[3][tid];
            cring[i & 3][tid] = cn;
        }
        __syncthreads();

        xp = xp_n; zxv = zx_n;
    }
#undef XLOAD
#undef XFIN
}

// ---------------------------------------------------------------------------
// decoder: out[e] += sum_l Wdo[l] * relu(bd[l] + sum_k Wd[l,k] feat[e,k])
// ---------------------------------------------------------------------------
__global__ __launch_bounds__(256) void k_dec(
    const __hip_bfloat16* __restrict__ arc_f, const __hip_bfloat16* __restrict__ arc_b,
    const float* __restrict__ Wd, const float* __restrict__ bd,
    const float* __restrict__ Wdo, float* __restrict__ out) {
    const int e0 = blockIdx.x * 128;
    const int l0 = blockIdx.y * 128;
    __shared__ __align__(16) float As[8][128];
    __shared__ __align__(16) float Bs[8][128];
    const int tid = threadIdx.x;
    const int tx = tid & 15, ty = tid >> 4;
    const int lr = tid & 127, kq = tid >> 7;

    const int e = e0 + lr;
    const int j = e >> 2, d = e & 3;
    const int jb = j - 1 - d;
    const __hip_bfloat16* frow  = arc_f + (size_t)e * kH;
    const __hip_bfloat16* brow2 = (jb >= 0) ? (arc_b + ((size_t)jb * 4 + d) * kH) : nullptr;
    const float* wrow = Wd + (size_t)(l0 + lr) * (2 * kH);

    float acc[8][8] = {};
    for (int k0 = 0; k0 < 2 * kH; k0 += 8) {
        const int kk = k0 + kq * 4;
        float4 av4;
        if (kk < kH) av4 = ld_bf4(frow + kk);
        else if (brow2) av4 = ld_bf4(brow2 + (kk - kH));
        else av4 = make_float4(0.f, 0.f, 0.f, 0.f);
        float4 bv4 = *(const float4*)(wrow + kk);
        __syncthreads();
        As[kq*4+0][lr] = av4.x; As[kq*4+1][lr] = av4.y;
        As[kq*4+2][lr] = av4.z; As[kq*4+3][lr] = av4.w;
        Bs[kq*4+0][lr] = bv4.x; Bs[kq*4+1][lr] = bv4.y;
        Bs[kq*4+2][lr] = bv4.z; Bs[kq*4+3][lr] = bv4.w;
        __syncthreads();
        #pragma unroll
        for (int kt = 0; kt < 8; kt++) {
            __align__(16) float a0[8], b0[8];
            *(float4*)&a0[0] = *(const float4*)&As[kt][ty*8];
            *(float4*)&a0[4] = *(const float4*)&As[kt][ty*8+4];
            *(float4*)&b0[0] = *(const float4*)&Bs[kt][tx*8];
            *(float4*)&b0[4] = *(const float4*)&Bs[kt][tx*8+4];
            #pragma unroll
            for (int mi = 0; mi < 8; mi++)
                #pragma unroll
                for (int ni = 0; ni < 8; ni++)
                    acc[mi][ni] += a0[mi] * b0[ni];
        }
    }
    #pragma unroll
    for (int mi = 0; mi < 8; mi++) {
        float sacc = 0.f;
        #pragma unroll
        for (int ni = 0; ni < 8; ni++) {
            int l = l0 + tx * 8 + ni;
            sacc += Wdo[l] * fmaxf(acc[mi][ni] + bd[l], 0.f);
        }
        sacc += __shfl_xor(sacc, 1);
        sacc += __shfl_xor(sacc, 2);
        sacc += __shfl_xor(sacc, 4);
        sacc += __shfl_xor(sacc, 8);
        if (tx == 0) atomicAdd(out + e0 + ty * 8 + mi, sacc);
    }
}

// ---------------------------------------------------------------------------
extern "C" void kernel_launch(void* const* d_in, const int* in_sizes, int n_in,
                              void* d_out, int out_size, void* d_ws, size_t ws_size,
                              hipStream_t stream) {
    const float* edges = (const float*)d_in[0];
    const float* Wih_f = (const float*)d_in[1];
    const float* Whh_f = (const float*)d_in[2];
    const float* b_f   = (const float*)d_in[3];
    const float* Wih_b = (const float*)d_in[4];
    const float* Whh_b = (const float*)d_in[5];
    const float* b_b   = (const float*)d_in[6];
    const float* Wa    = (const float*)d_in[7];
    const float* ba    = (const float*)d_in[8];
    const float* Wao   = (const float*)d_in[9];
    const float* bao   = (const float*)d_in[10];
    const float* Wd    = (const float*)d_in[11];
    const float* bd    = (const float*)d_in[12];
    const float* Wdo   = (const float*)d_in[13];
    const float* bdo   = (const float*)d_in[14];
    float* out = (float*)d_out;

    char* ws = (char*)d_ws;
    size_t off = 0;
    __hip_bfloat16* arc_f = (__hip_bfloat16*)(ws + off); off += (size_t)kE * kH * 2;  // 32 MB
    __hip_bfloat16* arc_b = (__hip_bfloat16*)(ws + off); off += (size_t)kE * kH * 2;  // 32 MB
    ull* hpay = (ull*)(ws + off); off += (size_t)2 * 2 * 4 * kH * 8;                  // 64 KB
    ull* zpay = (ull*)(ws + off); off += (size_t)2 * 2 * 32 * 256 * 8;                // 256 KB
    int* claims = (int*)(ws + off); off += 64;

    if (ws_size < off) {
        hipLaunchKernelGGL(k_zero, dim3((kE + 255) / 256), dim3(256), 0, stream, out);
        return;
    }

    hipLaunchKernelGGL(k_init, dim3(128), dim3(256), 0, stream, out, bdo, hpay, zpay, claims);
    hipLaunchKernelGGL(k_recur, dim3(512), dim3(256), 0, stream,
                       edges, Wih_f, Whh_f, b_f, Wih_b, Whh_b, b_b,
                       Wa, ba, Wao, bao, arc_f, arc_b, hpay, zpay, claims);
    hipLaunchKernelGGL(k_dec, dim3(kE / 128, kL / 128), dim3(256), 0, stream,
                       arc_f, arc_b, Wd, bd, Wdo, out);
}